// Round 8
// baseline (1406.467 us; speedup 1.0000x reference)
//
#include <hip/hip_runtime.h>
#include <math.h>

#define MAXNB 512
#define CHUNK 2048

// ---------------- utility ----------------

__global__ void copy_kernel(const float4* __restrict__ src, float4* __restrict__ dst, int n4) {
    int tid = blockIdx.x * blockDim.x + threadIdx.x;
    int stride = gridDim.x * blockDim.x;
    for (int i = tid; i < n4; i += stride) dst[i] = src[i];
}

// ---------------- binned edge reorganization ----------------

// global histogram of edges per 256-node bin (LDS-aggregated)
__global__ void binhist_kernel(const int* __restrict__ dst, int* __restrict__ binCnt,
                               int E, int NB) {
    __shared__ int h[MAXNB];
    for (int i = threadIdx.x; i < NB; i += blockDim.x) h[i] = 0;
    __syncthreads();
    int tid = blockIdx.x * blockDim.x + threadIdx.x;
    int stride = gridDim.x * blockDim.x;
    for (int e = tid; e < E; e += stride) atomicAdd(&h[dst[e] >> 8], 1);
    __syncthreads();
    for (int i = threadIdx.x; i < NB; i += blockDim.x) {
        int v = h[i];
        if (v) atomicAdd(&binCnt[i], v);
    }
}

// single wave: exclusive scan of binCnt -> binBase, init binCursor
__global__ void binscan_kernel(const int* __restrict__ binCnt, int* __restrict__ binBase,
                               int* __restrict__ binCursor, int NB, int E) {
    int lane = threadIdx.x;
    int running = 0;
    for (int c = 0; c * 64 < NB; ++c) {
        int idx = c * 64 + lane;
        int v = (idx < NB) ? binCnt[idx] : 0;
        int inc = v;
        for (int off = 1; off < 64; off <<= 1) {
            int u = __shfl_up(inc, off);
            if (lane >= off) inc += u;
        }
        int excl = running + inc - v;
        if (idx < NB) { binBase[idx] = excl; binCursor[idx] = excl; }
        running += __shfl(inc, 63);
    }
    if (lane == 0) binBase[NB] = E;
}

// chunk-local LDS bin-sort, then burst-write bin-contiguous (src,dst) pairs
__launch_bounds__(256, 4)
__global__ void phaseB_kernel(const int* __restrict__ src, const int* __restrict__ dst,
                              int* __restrict__ binCursor, int2* __restrict__ etmp,
                              int E, int NB) {
    __shared__ int hist[MAXNB], sbase[MAXNB], lcnt[MAXNB], adj[MAXNB];
    __shared__ int2 rb[CHUNK];
    int t = threadIdx.x, lane = t & 63, wv = t >> 6;
    int base = blockIdx.x * CHUNK;
    int ne = min(CHUNK, E - base);
    for (int i = t; i < NB; i += 256) { hist[i] = 0; lcnt[i] = 0; }
    __syncthreads();
    const int PT = CHUNK / 256;
    int rs[PT], rd[PT];
#pragma unroll
    for (int i = 0; i < PT; ++i) {
        int idx = i * 256 + t;
        if (idx < ne) {
            rs[i] = src[base + idx];
            rd[i] = dst[base + idx];
            atomicAdd(&hist[rd[i] >> 8], 1);
        } else rd[i] = -1;
    }
    __syncthreads();
    if (wv == 0) {                       // wave-scan of hist -> sbase (exclusive)
        int running = 0;
        for (int c = 0; c * 64 < NB; ++c) {
            int idx = c * 64 + lane;
            int v = (idx < NB) ? hist[idx] : 0;
            int inc = v;
            for (int off = 1; off < 64; off <<= 1) {
                int u = __shfl_up(inc, off);
                if (lane >= off) inc += u;
            }
            if (idx < NB) sbase[idx] = running + inc - v;
            running += __shfl(inc, 63);
        }
    }
    __syncthreads();
    for (int bIdx = t; bIdx < NB; bIdx += 256) {     // reserve global ranges
        int hcount = hist[bIdx];
        if (hcount) {
            int g = atomicAdd(&binCursor[bIdx], hcount);
            adj[bIdx] = g - sbase[bIdx];
        }
    }
    __syncthreads();
#pragma unroll
    for (int i = 0; i < PT; ++i) {                   // place into LDS bin-sorted
        if (rd[i] >= 0) {
            int bb = rd[i] >> 8;
            int off = atomicAdd(&lcnt[bb], 1);
            rb[sbase[bb] + off] = make_int2(rs[i], rd[i]);
        }
    }
    __syncthreads();
    for (int p = t; p < ne; p += 256) {              // burst copy-out
        int2 v = rb[p];
        etmp[p + adj[v.y >> 8]] = v;
    }
}

// per-bin degree via LDS histogram -> dinv
__global__ void dinvbin_kernel(const int2* __restrict__ etmp, const int* __restrict__ binBase,
                               float* __restrict__ dinv, int N) {
    __shared__ int c[256];
    int t = threadIdx.x, b = blockIdx.x;
    c[t] = 0;
    __syncthreads();
    int bb = binBase[b], ne = binBase[b + 1] - bb;
    for (int i = t; i < ne; i += 256) atomicAdd(&c[etmp[bb + i].y & 255], 1);
    __syncthreads();
    int v = b * 256 + t;
    if (v < N) dinv[v] = rsqrtf((float)(c[t] + 1));   // +1 self loop
}

// ---------------- layer kernels ----------------

// Ap[N,64] = (X[N,128] @ W1) * dinv[row]; W1 column in 128 regs, x row via
// per-wave LDS broadcast buffer.
__launch_bounds__(256, 2)
__global__ void rowgemm_kernel(const float* __restrict__ X, const float* __restrict__ W,
                               const float* __restrict__ dinv, float* __restrict__ Ap, int N) {
    __shared__ float xbuf[4][128];
    int lane = threadIdx.x & 63;
    int wv = threadIdx.x >> 6;
    float w[128];
#pragma unroll
    for (int k = 0; k < 128; ++k) w[k] = W[k * 64 + lane];
    int gtid = blockIdx.x * blockDim.x + threadIdx.x;
    int wave = gtid >> 6;
    int nw = (gridDim.x * blockDim.x) >> 6;
    const float4* xb4 = (const float4*)xbuf[wv];
    for (int v = wave; v < N; v += nw) {
        float2 x2 = *(const float2*)(X + (size_t)v * 128 + lane * 2);
        *(float2*)&xbuf[wv][lane * 2] = x2;
        asm volatile("s_waitcnt lgkmcnt(0)" ::: "memory");
        float acc = 0.f;
#pragma unroll
        for (int k4 = 0; k4 < 32; ++k4) {
            float4 xv = xb4[k4];
            acc += xv.x * w[4 * k4 + 0] + xv.y * w[4 * k4 + 1]
                 + xv.z * w[4 * k4 + 2] + xv.w * w[4 * k4 + 3];
        }
        Ap[(size_t)v * 64 + lane] = acc * dinv[v];
        asm volatile("s_waitcnt lgkmcnt(0)" ::: "memory");
    }
}

// per-bin: LDS-accumulate gathered Ap rows, then h=relu + fused GEMM2 -> A2p
__launch_bounds__(256, 2)
__global__ void midbin_kernel(const float* __restrict__ Ap, const int2* __restrict__ etmp,
                              const int* __restrict__ binBase, const float* __restrict__ dinv,
                              const float* __restrict__ W2, const float* __restrict__ b1,
                              float* __restrict__ A2p, int N) {
    __shared__ float acc[256][64];
    __shared__ int2 ebuf[4][64];
    __shared__ float hbuf[4][64];
    int t = threadIdx.x, lane = t & 63, wv = t >> 6;
    int b = blockIdx.x;
    float4* az = (float4*)&acc[0][0];
    for (int i = t; i < 256 * 64 / 4; i += 256) az[i] = make_float4(0.f, 0.f, 0.f, 0.f);
    int cidx = lane < 40 ? lane : 0;
    float w2[64];
#pragma unroll
    for (int k = 0; k < 64; ++k) w2[k] = W2[k * 40 + cidx];
    float bias = b1[lane];
    __syncthreads();
    int bb = binBase[b], ne = binBase[b + 1] - bb;
    for (int base0 = wv * 64; base0 < ne; base0 += 256) {
        int n = min(64, ne - base0);
        if (lane < n) ebuf[wv][lane] = etmp[bb + base0 + lane];
        asm volatile("s_waitcnt lgkmcnt(0)" ::: "memory");
        int j = 0;
        for (; j + 4 <= n; j += 4) {
            int2 e0 = ebuf[wv][j], e1 = ebuf[wv][j + 1];
            int2 e2 = ebuf[wv][j + 2], e3 = ebuf[wv][j + 3];
            float f0 = Ap[(size_t)e0.x * 64 + lane];
            float f1 = Ap[(size_t)e1.x * 64 + lane];
            float f2 = Ap[(size_t)e2.x * 64 + lane];
            float f3 = Ap[(size_t)e3.x * 64 + lane];
            atomicAdd(&acc[e0.y & 255][lane], f0);
            atomicAdd(&acc[e1.y & 255][lane], f1);
            atomicAdd(&acc[e2.y & 255][lane], f2);
            atomicAdd(&acc[e3.y & 255][lane], f3);
        }
        for (; j < n; ++j) {
            int2 e = ebuf[wv][j];
            atomicAdd(&acc[e.y & 255][lane], Ap[(size_t)e.x * 64 + lane]);
        }
    }
    __syncthreads();
    int nnodes = min(256, N - b * 256);
    const float4* hb4 = (const float4*)hbuf[wv];
    for (int nl = wv; nl < nnodes; nl += 4) {
        int v = b * 256 + nl;
        float dv = dinv[v];
        float h = dv * (acc[nl][lane] + Ap[(size_t)v * 64 + lane] * dv) + bias;
        h = h > 0.f ? h : 0.f;
        hbuf[wv][lane] = h;
        asm volatile("s_waitcnt lgkmcnt(0)" ::: "memory");
        float a2 = 0.f;
#pragma unroll
        for (int k4 = 0; k4 < 16; ++k4) {
            float4 hv = hb4[k4];
            a2 += hv.x * w2[4 * k4 + 0] + hv.y * w2[4 * k4 + 1]
                + hv.z * w2[4 * k4 + 2] + hv.w * w2[4 * k4 + 3];
        }
        if (lane < 40) A2p[(size_t)v * 40 + lane] = a2 * dv;
        asm volatile("s_waitcnt lgkmcnt(0)" ::: "memory");
    }
}

// per-bin: LDS-accumulate gathered A2p rows, then bias + double softmax -> out
__global__ void outbin_kernel(const float* __restrict__ A2p, const int2* __restrict__ etmp,
                              const int* __restrict__ binBase, const float* __restrict__ dinv,
                              const float* __restrict__ b2, float* __restrict__ out, int N) {
    __shared__ float acc[256][40];
    __shared__ int2 ebuf[4][64];
    int t = threadIdx.x, lane = t & 63, wv = t >> 6;
    int b = blockIdx.x;
    float4* az = (float4*)&acc[0][0];
    for (int i = t; i < 256 * 40 / 4; i += 256) az[i] = make_float4(0.f, 0.f, 0.f, 0.f);
    __syncthreads();
    int bb = binBase[b], ne = binBase[b + 1] - bb;
    for (int base0 = wv * 64; base0 < ne; base0 += 256) {
        int n = min(64, ne - base0);
        if (lane < n) ebuf[wv][lane] = etmp[bb + base0 + lane];
        asm volatile("s_waitcnt lgkmcnt(0)" ::: "memory");
        int j = 0;
        for (; j + 4 <= n; j += 4) {
            int2 e0 = ebuf[wv][j], e1 = ebuf[wv][j + 1];
            int2 e2 = ebuf[wv][j + 2], e3 = ebuf[wv][j + 3];
            if (lane < 40) {
                float f0 = A2p[(size_t)e0.x * 40 + lane];
                float f1 = A2p[(size_t)e1.x * 40 + lane];
                float f2 = A2p[(size_t)e2.x * 40 + lane];
                float f3 = A2p[(size_t)e3.x * 40 + lane];
                atomicAdd(&acc[e0.y & 255][lane], f0);
                atomicAdd(&acc[e1.y & 255][lane], f1);
                atomicAdd(&acc[e2.y & 255][lane], f2);
                atomicAdd(&acc[e3.y & 255][lane], f3);
            }
        }
        for (; j < n; ++j) {
            int2 e = ebuf[wv][j];
            if (lane < 40) atomicAdd(&acc[e.y & 255][lane], A2p[(size_t)e.x * 40 + lane]);
        }
    }
    __syncthreads();
    int nnodes = min(256, N - b * 256);
    for (int nl = wv; nl < nnodes; nl += 4) {
        int v = b * 256 + nl;
        bool act = lane < 40;
        float dv = dinv[v];
        float z = act ? dv * (acc[nl][lane] + A2p[(size_t)v * 40 + lane] * dv) + b2[lane]
                      : -INFINITY;
        float m = z;
        for (int off = 32; off; off >>= 1) m = fmaxf(m, __shfl_xor(m, off));
        float e = act ? expf(z - m) : 0.f;
        float s = e;
        for (int off = 32; off; off >>= 1) s += __shfl_xor(s, off);
        float p = e / s;
        float m2 = act ? p : -INFINITY;
        for (int off = 32; off; off >>= 1) m2 = fmaxf(m2, __shfl_xor(m2, off));
        float e2 = act ? expf(p - m2) : 0.f;
        float s2 = e2;
        for (int off = 32; off; off >>= 1) s2 += __shfl_xor(s2, off);
        if (act) out[(size_t)v * 40 + lane] = (p - m2) - logf(s2);
    }
}

// ---------------- launch ----------------

extern "C" void kernel_launch(void* const* d_in, const int* in_sizes, int n_in,
                              void* d_out, int out_size, void* d_ws, size_t ws_size,
                              hipStream_t stream) {
    const float* x_in  = (const float*)d_in[0];
    const int*   ei    = (const int*)d_in[1];
    const float* W1_in = (const float*)d_in[2];
    const float* b1_in = (const float*)d_in[3];
    const float* W2_in = (const float*)d_in[4];
    const float* b2_in = (const float*)d_in[5];
    float* out = (float*)d_out;

    int N = in_sizes[0] / 128;
    int E = in_sizes[1] / 2;
    const int* src = ei;
    const int* dst = ei + E;
    int NB = (N + 255) >> 8;            // 256-node bins

    char* ws = (char*)d_ws;
    size_t o = 0;
    auto alloc = [&](size_t bytes) { void* p = ws + o; o += (bytes + 255) & ~(size_t)255; return p; };
    int*   binCnt    = (int*)alloc((size_t)MAXNB * 4);
    int*   binBase   = (int*)alloc(((size_t)MAXNB + 1) * 4);
    int*   binCursor = (int*)alloc((size_t)MAXNB * 4);
    float* dinv      = (float*)alloc((size_t)N * 4);
    int2*  etmp      = (int2*)alloc((size_t)E * 8);
    float* Ap        = (float*)alloc((size_t)N * 64 * 4);
    float* A2p       = (float*)alloc((size_t)N * 40 * 4);
    float* W1c = (float*)alloc(128 * 64 * 4);
    float* W2c = (float*)alloc(64 * 40 * 4);
    float* b1c = (float*)alloc(64 * 4);
    float* b2c = (float*)alloc(40 * 4);

    // stage small fp32 params
    copy_kernel<<<8, 256, 0, stream>>>((const float4*)W1_in, (float4*)W1c, 128 * 64 / 4);
    copy_kernel<<<4, 256, 0, stream>>>((const float4*)W2_in, (float4*)W2c, 64 * 40 / 4);
    copy_kernel<<<1, 64, 0, stream>>>((const float4*)b1_in, (float4*)b1c, 16);
    copy_kernel<<<1, 64, 0, stream>>>((const float4*)b2_in, (float4*)b2c, 10);

    // binned edge reorganization
    hipMemsetAsync(binCnt, 0, (size_t)MAXNB * 4, stream);
    binhist_kernel<<<512, 256, 0, stream>>>(dst, binCnt, E, NB);
    binscan_kernel<<<1, 64, 0, stream>>>(binCnt, binBase, binCursor, NB, E);
    phaseB_kernel<<<(E + CHUNK - 1) / CHUNK, 256, 0, stream>>>(src, dst, binCursor, etmp, E, NB);
    dinvbin_kernel<<<NB, 256, 0, stream>>>(etmp, binBase, dinv, N);

    // layers
    rowgemm_kernel<<<1024, 256, 0, stream>>>(x_in, W1c, dinv, Ap, N);
    midbin_kernel<<<NB, 256, 0, stream>>>(Ap, etmp, binBase, dinv, W2c, b1c, A2p, N);
    outbin_kernel<<<NB, 256, 0, stream>>>(A2p, etmp, binBase, dinv, b2c, out, N);
}

// Round 9
// 305.383 us; speedup vs baseline: 4.6056x; 4.6056x over previous
//
#include <hip/hip_runtime.h>
#include <math.h>

#define MAXNB 512
#define CHUNK 4096

// ---------------- utility ----------------

__global__ void copy_kernel(const float4* __restrict__ src, float4* __restrict__ dst, int n4) {
    int tid = blockIdx.x * blockDim.x + threadIdx.x;
    int stride = gridDim.x * blockDim.x;
    for (int i = tid; i < n4; i += stride) dst[i] = src[i];
}

// ---------------- binned CSR build ----------------

// global histogram of edges per 256-node bin (LDS-aggregated)
__global__ void binhist_kernel(const int* __restrict__ dst, int* __restrict__ binCnt,
                               int E, int NB) {
    __shared__ int h[MAXNB];
    for (int i = threadIdx.x; i < NB; i += blockDim.x) h[i] = 0;
    __syncthreads();
    int tid = blockIdx.x * blockDim.x + threadIdx.x;
    int stride = gridDim.x * blockDim.x;
    for (int e = tid; e < E; e += stride) atomicAdd(&h[dst[e] >> 8], 1);
    __syncthreads();
    for (int i = threadIdx.x; i < NB; i += blockDim.x) {
        int v = h[i];
        if (v) atomicAdd(&binCnt[i], v);
    }
}

// single wave: exclusive scan of binCnt -> binBase, init binCursor; rowptr[N]=E
__global__ void binscan_kernel(const int* __restrict__ binCnt, int* __restrict__ binBase,
                               int* __restrict__ binCursor, int* __restrict__ rowptr,
                               int NB, int N, int E) {
    int lane = threadIdx.x;
    int running = 0;
    for (int c = 0; c * 64 < NB; ++c) {
        int idx = c * 64 + lane;
        int v = (idx < NB) ? binCnt[idx] : 0;
        int inc = v;
        for (int off = 1; off < 64; off <<= 1) {
            int u = __shfl_up(inc, off);
            if (lane >= off) inc += u;
        }
        int excl = running + inc - v;
        if (idx < NB) { binBase[idx] = excl; binCursor[idx] = excl; }
        running += __shfl(inc, 63);
    }
    if (lane == 0) { binBase[NB] = E; rowptr[N] = E; }
}

// chunk-local LDS bin-sort, then burst-write bin-contiguous (src,dst) pairs
__launch_bounds__(256, 4)
__global__ void phaseB_kernel(const int* __restrict__ src, const int* __restrict__ dst,
                              int* __restrict__ binCursor, int2* __restrict__ etmp,
                              int E, int NB) {
    __shared__ int hist[MAXNB], sbase[MAXNB], lcnt[MAXNB], adj[MAXNB];
    __shared__ int2 rb[CHUNK];
    int t = threadIdx.x, lane = t & 63, wv = t >> 6;
    int base = blockIdx.x * CHUNK;
    int ne = min(CHUNK, E - base);
    for (int i = t; i < NB; i += 256) { hist[i] = 0; lcnt[i] = 0; }
    __syncthreads();
    const int PT = CHUNK / 256;
    int rs[PT], rd[PT];
#pragma unroll
    for (int i = 0; i < PT; ++i) {
        int idx = i * 256 + t;
        if (idx < ne) {
            rs[i] = src[base + idx];
            rd[i] = dst[base + idx];
            atomicAdd(&hist[rd[i] >> 8], 1);
        } else rd[i] = -1;
    }
    __syncthreads();
    if (wv == 0) {                       // wave-scan of hist -> sbase (exclusive)
        int running = 0;
        for (int c = 0; c * 64 < NB; ++c) {
            int idx = c * 64 + lane;
            int v = (idx < NB) ? hist[idx] : 0;
            int inc = v;
            for (int off = 1; off < 64; off <<= 1) {
                int u = __shfl_up(inc, off);
                if (lane >= off) inc += u;
            }
            if (idx < NB) sbase[idx] = running + inc - v;
            running += __shfl(inc, 63);
        }
    }
    __syncthreads();
    for (int bIdx = t; bIdx < NB; bIdx += 256) {     // reserve global ranges
        int hcount = hist[bIdx];
        if (hcount) {
            int g = atomicAdd(&binCursor[bIdx], hcount);
            adj[bIdx] = g - sbase[bIdx];
        }
    }
    __syncthreads();
#pragma unroll
    for (int i = 0; i < PT; ++i) {                   // place into LDS bin-sorted
        if (rd[i] >= 0) {
            int bb = rd[i] >> 8;
            int off = atomicAdd(&lcnt[bb], 1);
            rb[sbase[bb] + off] = make_int2(rs[i], rd[i]);
        }
    }
    __syncthreads();
    for (int p = t; p < ne; p += 256) {              // burst copy-out
        int2 v = rb[p];
        etmp[p + adj[v.y >> 8]] = v;
    }
}

// block per bin: node histogram -> rowptr + dinv, then node-contiguous esrc.
// Scatter writes confined to the bin's ~16KB region (L2-resident).
__global__ void bin2csr_kernel(const int2* __restrict__ etmp, const int* __restrict__ binBase,
                               int* __restrict__ rowptr, float* __restrict__ dinv,
                               int* __restrict__ esrc, int N) {
    __shared__ int hist[256], lcur[256], wsum[4];
    int t = threadIdx.x, b = blockIdx.x;
    hist[t] = 0;
    __syncthreads();
    int bb = binBase[b], ne = binBase[b + 1] - bb;
    for (int i = t; i < ne; i += 256) atomicAdd(&hist[etmp[bb + i].y & 255], 1);
    __syncthreads();
    int lane = t & 63, wv = t >> 6;
    int v = hist[t];
    int inc = v;
    for (int off = 1; off < 64; off <<= 1) {
        int u = __shfl_up(inc, off);
        if (lane >= off) inc += u;
    }
    if (lane == 63) wsum[wv] = inc;
    __syncthreads();
    int woff = 0;
    for (int i = 0; i < wv; ++i) woff += wsum[i];
    int excl = woff + inc - v;
    int node = b * 256 + t;
    if (node < N) {
        rowptr[node] = bb + excl;
        dinv[node] = rsqrtf((float)(v + 1));   // +1 self loop
    }
    lcur[t] = excl;
    __syncthreads();
    for (int i = t; i < ne; i += 256) {
        int2 e = etmp[bb + i];
        int p = atomicAdd(&lcur[e.y & 255], 1);
        esrc[bb + p] = e.x;
    }
}

// ---------------- layer kernels ----------------

// Ap[N,64] = (X[N,128] @ W1) * dinv[row]; W1 column in 128 regs, x row via
// per-wave LDS broadcast buffer.
__launch_bounds__(256, 2)
__global__ void rowgemm_kernel(const float* __restrict__ X, const float* __restrict__ W,
                               const float* __restrict__ dinv, float* __restrict__ Ap, int N) {
    __shared__ float xbuf[4][128];
    int lane = threadIdx.x & 63;
    int wv = threadIdx.x >> 6;
    float w[128];
#pragma unroll
    for (int k = 0; k < 128; ++k) w[k] = W[k * 64 + lane];
    int gtid = blockIdx.x * blockDim.x + threadIdx.x;
    int wave = gtid >> 6;
    int nw = (gridDim.x * blockDim.x) >> 6;
    const float4* xb4 = (const float4*)xbuf[wv];
    for (int v = wave; v < N; v += nw) {
        float2 x2 = *(const float2*)(X + (size_t)v * 128 + lane * 2);
        *(float2*)&xbuf[wv][lane * 2] = x2;
        asm volatile("s_waitcnt lgkmcnt(0)" ::: "memory");
        float acc = 0.f;
#pragma unroll
        for (int k4 = 0; k4 < 32; ++k4) {
            float4 xv = xb4[k4];
            acc += xv.x * w[4 * k4 + 0] + xv.y * w[4 * k4 + 1]
                 + xv.z * w[4 * k4 + 2] + xv.w * w[4 * k4 + 3];
        }
        Ap[(size_t)v * 64 + lane] = acc * dinv[v];
        asm volatile("s_waitcnt lgkmcnt(0)" ::: "memory");
    }
}

// Wave per node: gather Ap rows via CSR, h = relu(dinv*(sum + Ap[v]*dinv) + b1),
// then fused GEMM2 with W2 column in 64 regs, h via per-wave LDS broadcast buffer.
__launch_bounds__(256, 2)
__global__ void layer_mid_kernel(const float* __restrict__ Ap, const int* __restrict__ esrc,
                                 const int* __restrict__ rowptr, const float* __restrict__ dinv,
                                 const float* __restrict__ W2, const float* __restrict__ b1,
                                 float* __restrict__ A2p, int N) {
    __shared__ float hbuf[4][64];
    int lane = threadIdx.x & 63;
    int wv = threadIdx.x >> 6;
    int cidx = lane < 40 ? lane : 0;
    float w2[64];
#pragma unroll
    for (int k = 0; k < 64; ++k) w2[k] = W2[k * 40 + cidx];
    float bias = b1[lane];
    int gtid = blockIdx.x * blockDim.x + threadIdx.x;
    int wave = gtid >> 6;
    int nw = (gridDim.x * blockDim.x) >> 6;
    const float4* hb4 = (const float4*)hbuf[wv];
    for (int v = wave; v < N; v += nw) {
        int i0 = rowptr[v], i1 = rowptr[v + 1];
        float acc = 0.f;
        for (int base = i0; base < i1; base += 64) {
            int n = min(64, i1 - base);
            int el = (lane < n) ? esrc[base + lane] : 0;
            int j = 0;
            for (; j + 4 <= n; j += 4) {
                int s0 = __shfl(el, j), s1 = __shfl(el, j + 1);
                int s2 = __shfl(el, j + 2), s3 = __shfl(el, j + 3);
                float f0 = Ap[(size_t)s0 * 64 + lane];
                float f1 = Ap[(size_t)s1 * 64 + lane];
                float f2 = Ap[(size_t)s2 * 64 + lane];
                float f3 = Ap[(size_t)s3 * 64 + lane];
                acc += f0; acc += f1; acc += f2; acc += f3;
            }
            for (; j < n; ++j) {
                int s0 = __shfl(el, j);
                acc += Ap[(size_t)s0 * 64 + lane];
            }
        }
        float dv = dinv[v];
        float h = dv * (acc + Ap[(size_t)v * 64 + lane] * dv) + bias;
        h = h > 0.f ? h : 0.f;
        hbuf[wv][lane] = h;
        asm volatile("s_waitcnt lgkmcnt(0)" ::: "memory");
        float a2 = 0.f;
#pragma unroll
        for (int k4 = 0; k4 < 16; ++k4) {
            float4 hv = hb4[k4];
            a2 += hv.x * w2[4 * k4 + 0] + hv.y * w2[4 * k4 + 1]
                + hv.z * w2[4 * k4 + 2] + hv.w * w2[4 * k4 + 3];
        }
        if (lane < 40) A2p[(size_t)v * 40 + lane] = a2 * dv;
        asm volatile("s_waitcnt lgkmcnt(0)" ::: "memory");
    }
}

// Wave per node: gather A2p rows, z = dinv*(sum + A2p[v]*dinv) + b2,
// out = log_softmax(softmax(z)) over 40 cols.
__global__ void layer_out_kernel(const float* __restrict__ A2p, const int* __restrict__ esrc,
                                 const int* __restrict__ rowptr, const float* __restrict__ dinv,
                                 const float* __restrict__ b2, float* __restrict__ out, int N) {
    int gtid = blockIdx.x * blockDim.x + threadIdx.x;
    int wave = gtid >> 6, lane = threadIdx.x & 63;
    int nw = (gridDim.x * blockDim.x) >> 6;
    for (int v = wave; v < N; v += nw) {
        int i0 = rowptr[v], i1 = rowptr[v + 1];
        bool act = lane < 40;
        float acc = 0.f;
        for (int base = i0; base < i1; base += 64) {
            int n = min(64, i1 - base);
            int el = (lane < n) ? esrc[base + lane] : 0;
            int j = 0;
            for (; j + 4 <= n; j += 4) {
                int s0 = __shfl(el, j), s1 = __shfl(el, j + 1);
                int s2 = __shfl(el, j + 2), s3 = __shfl(el, j + 3);
                if (act) {
                    float f0 = A2p[(size_t)s0 * 40 + lane];
                    float f1 = A2p[(size_t)s1 * 40 + lane];
                    float f2 = A2p[(size_t)s2 * 40 + lane];
                    float f3 = A2p[(size_t)s3 * 40 + lane];
                    acc += f0; acc += f1; acc += f2; acc += f3;
                }
            }
            for (; j < n; ++j) {
                int s0 = __shfl(el, j);
                if (act) acc += A2p[(size_t)s0 * 40 + lane];
            }
        }
        float dv = dinv[v];
        float z = act ? dv * (acc + A2p[(size_t)v * 40 + lane] * dv) + b2[lane] : -INFINITY;
        float m = z;
        for (int off = 32; off; off >>= 1) m = fmaxf(m, __shfl_xor(m, off));
        float e = act ? expf(z - m) : 0.f;
        float s = e;
        for (int off = 32; off; off >>= 1) s += __shfl_xor(s, off);
        float p = e / s;
        float m2 = act ? p : -INFINITY;
        for (int off = 32; off; off >>= 1) m2 = fmaxf(m2, __shfl_xor(m2, off));
        float e2 = act ? expf(p - m2) : 0.f;
        float s2 = e2;
        for (int off = 32; off; off >>= 1) s2 += __shfl_xor(s2, off);
        if (act) out[(size_t)v * 40 + lane] = (p - m2) - logf(s2);
    }
}

// ---------------- launch ----------------

extern "C" void kernel_launch(void* const* d_in, const int* in_sizes, int n_in,
                              void* d_out, int out_size, void* d_ws, size_t ws_size,
                              hipStream_t stream) {
    const float* x_in  = (const float*)d_in[0];
    const int*   ei    = (const int*)d_in[1];
    const float* W1_in = (const float*)d_in[2];
    const float* b1_in = (const float*)d_in[3];
    const float* W2_in = (const float*)d_in[4];
    const float* b2_in = (const float*)d_in[5];
    float* out = (float*)d_out;

    int N = in_sizes[0] / 128;
    int E = in_sizes[1] / 2;
    const int* src = ei;
    const int* dst = ei + E;
    int NB = (N + 255) >> 8;            // 256-node bins

    char* ws = (char*)d_ws;
    size_t o = 0;
    auto alloc = [&](size_t bytes) { void* p = ws + o; o += (bytes + 255) & ~(size_t)255; return p; };
    int*   binCnt    = (int*)alloc((size_t)MAXNB * 4);
    int*   binBase   = (int*)alloc(((size_t)MAXNB + 1) * 4);
    int*   binCursor = (int*)alloc((size_t)MAXNB * 4);
    float* dinv      = (float*)alloc((size_t)N * 4);
    int*   rowptr    = (int*)alloc(((size_t)N + 1) * 4);
    int2*  etmp      = (int2*)alloc((size_t)E * 8);
    int*   esrc      = (int*)alloc((size_t)E * 4);
    float* Ap        = (float*)alloc((size_t)N * 64 * 4);
    float* A2p       = (float*)alloc((size_t)N * 40 * 4);
    float* W1c = (float*)alloc(128 * 64 * 4);
    float* W2c = (float*)alloc(64 * 40 * 4);
    float* b1c = (float*)alloc(64 * 4);
    float* b2c = (float*)alloc(40 * 4);

    // stage small fp32 params
    copy_kernel<<<8, 256, 0, stream>>>((const float4*)W1_in, (float4*)W1c, 128 * 64 / 4);
    copy_kernel<<<4, 256, 0, stream>>>((const float4*)W2_in, (float4*)W2c, 64 * 40 / 4);
    copy_kernel<<<1, 64, 0, stream>>>((const float4*)b1_in, (float4*)b1c, 16);
    copy_kernel<<<1, 64, 0, stream>>>((const float4*)b2_in, (float4*)b2c, 10);

    // binned CSR build
    hipMemsetAsync(binCnt, 0, (size_t)MAXNB * 4, stream);
    binhist_kernel<<<512, 256, 0, stream>>>(dst, binCnt, E, NB);
    binscan_kernel<<<1, 64, 0, stream>>>(binCnt, binBase, binCursor, rowptr, NB, N, E);
    phaseB_kernel<<<(E + CHUNK - 1) / CHUNK, 256, 0, stream>>>(src, dst, binCursor, etmp, E, NB);
    bin2csr_kernel<<<NB, 256, 0, stream>>>(etmp, binBase, rowptr, dinv, esrc, N);

    // layers
    rowgemm_kernel<<<1024, 256, 0, stream>>>(x_in, W1c, dinv, Ap, N);
    layer_mid_kernel<<<2048, 256, 0, stream>>>(Ap, esrc, rowptr, dinv, W2c, b1c, A2p, N);
    layer_out_kernel<<<2048, 256, 0, stream>>>(A2p, esrc, rowptr, dinv, b2c, out, N);
}

// Round 10
// 262.182 us; speedup vs baseline: 5.3645x; 1.1648x over previous
//
#include <hip/hip_runtime.h>
#include <math.h>

#define MAXNB 512
#define CHUNK 4096

__device__ inline float bf2f(unsigned short u) { return __uint_as_float(((unsigned)u) << 16); }
__device__ inline unsigned short f2bf(float f) {
    unsigned u = __float_as_uint(f);
    u += 0x7fff + ((u >> 16) & 1);          // round to nearest even
    return (unsigned short)(u >> 16);
}

// ---------------- utility ----------------

__global__ void copy_kernel(const float4* __restrict__ src, float4* __restrict__ dst, int n4) {
    int tid = blockIdx.x * blockDim.x + threadIdx.x;
    int stride = gridDim.x * blockDim.x;
    for (int i = tid; i < n4; i += stride) dst[i] = src[i];
}

// ---------------- binned CSR build ----------------

__global__ void binhist_kernel(const int* __restrict__ dst, int* __restrict__ binCnt,
                               int E, int NB) {
    __shared__ int h[MAXNB];
    for (int i = threadIdx.x; i < NB; i += blockDim.x) h[i] = 0;
    __syncthreads();
    int tid = blockIdx.x * blockDim.x + threadIdx.x;
    int stride = gridDim.x * blockDim.x;
    for (int e = tid; e < E; e += stride) atomicAdd(&h[dst[e] >> 8], 1);
    __syncthreads();
    for (int i = threadIdx.x; i < NB; i += blockDim.x) {
        int v = h[i];
        if (v) atomicAdd(&binCnt[i], v);
    }
}

__global__ void binscan_kernel(const int* __restrict__ binCnt, int* __restrict__ binBase,
                               int* __restrict__ binCursor, int* __restrict__ rowptr,
                               int NB, int N, int E) {
    int lane = threadIdx.x;
    int running = 0;
    for (int c = 0; c * 64 < NB; ++c) {
        int idx = c * 64 + lane;
        int v = (idx < NB) ? binCnt[idx] : 0;
        int inc = v;
        for (int off = 1; off < 64; off <<= 1) {
            int u = __shfl_up(inc, off);
            if (lane >= off) inc += u;
        }
        int excl = running + inc - v;
        if (idx < NB) { binBase[idx] = excl; binCursor[idx] = excl; }
        running += __shfl(inc, 63);
    }
    if (lane == 0) { binBase[NB] = E; rowptr[N] = E; }
}

__launch_bounds__(256, 4)
__global__ void phaseB_kernel(const int* __restrict__ src, const int* __restrict__ dst,
                              int* __restrict__ binCursor, int2* __restrict__ etmp,
                              int E, int NB) {
    __shared__ int hist[MAXNB], sbase[MAXNB], lcnt[MAXNB], adj[MAXNB];
    __shared__ int2 rb[CHUNK];
    int t = threadIdx.x, lane = t & 63, wv = t >> 6;
    int base = blockIdx.x * CHUNK;
    int ne = min(CHUNK, E - base);
    for (int i = t; i < NB; i += 256) { hist[i] = 0; lcnt[i] = 0; }
    __syncthreads();
    const int PT = CHUNK / 256;
    int rs[PT], rd[PT];
#pragma unroll
    for (int i = 0; i < PT; ++i) {
        int idx = i * 256 + t;
        if (idx < ne) {
            rs[i] = src[base + idx];
            rd[i] = dst[base + idx];
            atomicAdd(&hist[rd[i] >> 8], 1);
        } else rd[i] = -1;
    }
    __syncthreads();
    if (wv == 0) {
        int running = 0;
        for (int c = 0; c * 64 < NB; ++c) {
            int idx = c * 64 + lane;
            int v = (idx < NB) ? hist[idx] : 0;
            int inc = v;
            for (int off = 1; off < 64; off <<= 1) {
                int u = __shfl_up(inc, off);
                if (lane >= off) inc += u;
            }
            if (idx < NB) sbase[idx] = running + inc - v;
            running += __shfl(inc, 63);
        }
    }
    __syncthreads();
    for (int bIdx = t; bIdx < NB; bIdx += 256) {
        int hcount = hist[bIdx];
        if (hcount) {
            int g = atomicAdd(&binCursor[bIdx], hcount);
            adj[bIdx] = g - sbase[bIdx];
        }
    }
    __syncthreads();
#pragma unroll
    for (int i = 0; i < PT; ++i) {
        if (rd[i] >= 0) {
            int bb = rd[i] >> 8;
            int off = atomicAdd(&lcnt[bb], 1);
            rb[sbase[bb] + off] = make_int2(rs[i], rd[i]);
        }
    }
    __syncthreads();
    for (int p = t; p < ne; p += 256) {
        int2 v = rb[p];
        etmp[p + adj[v.y >> 8]] = v;
    }
}

__global__ void bin2csr_kernel(const int2* __restrict__ etmp, const int* __restrict__ binBase,
                               int* __restrict__ rowptr, float* __restrict__ dinv,
                               int* __restrict__ esrc, int N) {
    __shared__ int hist[256], lcur[256], wsum[4];
    int t = threadIdx.x, b = blockIdx.x;
    hist[t] = 0;
    __syncthreads();
    int bb = binBase[b], ne = binBase[b + 1] - bb;
    for (int i = t; i < ne; i += 256) atomicAdd(&hist[etmp[bb + i].y & 255], 1);
    __syncthreads();
    int lane = t & 63, wv = t >> 6;
    int v = hist[t];
    int inc = v;
    for (int off = 1; off < 64; off <<= 1) {
        int u = __shfl_up(inc, off);
        if (lane >= off) inc += u;
    }
    if (lane == 63) wsum[wv] = inc;
    __syncthreads();
    int woff = 0;
    for (int i = 0; i < wv; ++i) woff += wsum[i];
    int excl = woff + inc - v;
    int node = b * 256 + t;
    if (node < N) {
        rowptr[node] = bb + excl;
        dinv[node] = rsqrtf((float)(v + 1));   // +1 self loop
    }
    lcur[t] = excl;
    __syncthreads();
    for (int i = t; i < ne; i += 256) {
        int2 e = etmp[bb + i];
        int p = atomicAdd(&lcur[e.y & 255], 1);
        esrc[bb + p] = e.x;
    }
}

// ---------------- layer kernels ----------------

// Apb[N,64](bf16) = (X[N,128] @ W1) * dinv[row]; W1 column in 128 regs, x row
// via per-wave LDS broadcast buffer, next-row global prefetch.
__launch_bounds__(256, 2)
__global__ void rowgemm_kernel(const float* __restrict__ X, const float* __restrict__ W,
                               const float* __restrict__ dinv,
                               unsigned short* __restrict__ Apb, int N) {
    __shared__ float xbuf[4][128];
    int lane = threadIdx.x & 63;
    int wv = threadIdx.x >> 6;
    float w[128];
#pragma unroll
    for (int k = 0; k < 128; ++k) w[k] = W[k * 64 + lane];
    int wave = (blockIdx.x * blockDim.x + threadIdx.x) >> 6;
    int nw = (gridDim.x * blockDim.x) >> 6;
    const float4* xb4 = (const float4*)xbuf[wv];
    int v = wave;
    float2 x2 = make_float2(0.f, 0.f);
    if (v < N) x2 = *(const float2*)(X + (size_t)v * 128 + lane * 2);
    while (v < N) {
        *(float2*)&xbuf[wv][lane * 2] = x2;
        int vn = v + nw;
        float2 xn = make_float2(0.f, 0.f);
        if (vn < N) xn = *(const float2*)(X + (size_t)vn * 128 + lane * 2);  // prefetch
        float dv = dinv[v];
        asm volatile("s_waitcnt lgkmcnt(0)" ::: "memory");
        float acc = 0.f;
#pragma unroll
        for (int k4 = 0; k4 < 32; ++k4) {
            float4 xv = xb4[k4];
            acc += xv.x * w[4 * k4 + 0] + xv.y * w[4 * k4 + 1]
                 + xv.z * w[4 * k4 + 2] + xv.w * w[4 * k4 + 3];
        }
        Apb[(size_t)v * 64 + lane] = f2bf(acc * dv);
        asm volatile("s_waitcnt lgkmcnt(0)" ::: "memory");
        v = vn; x2 = xn;
    }
}

// Wave per node: gather bf16 Ap rows via CSR (fp32 accumulate),
// h = relu(dinv*(sum + Ap[v]*dinv) + b1), fused GEMM2 (W2 cols in regs,
// h via per-wave LDS broadcast) -> A2pb bf16.
__launch_bounds__(256, 2)
__global__ void layer_mid_kernel(const unsigned short* __restrict__ Apb,
                                 const int* __restrict__ esrc,
                                 const int* __restrict__ rowptr, const float* __restrict__ dinv,
                                 const float* __restrict__ W2, const float* __restrict__ b1,
                                 unsigned short* __restrict__ A2pb, int N) {
    __shared__ float hbuf[4][64];
    int lane = threadIdx.x & 63;
    int wv = threadIdx.x >> 6;
    int cidx = lane < 40 ? lane : 0;
    float w2[64];
#pragma unroll
    for (int k = 0; k < 64; ++k) w2[k] = W2[k * 40 + cidx];
    float bias = b1[lane];
    int gtid = blockIdx.x * blockDim.x + threadIdx.x;
    int wave = gtid >> 6;
    int nw = (gridDim.x * blockDim.x) >> 6;
    const float4* hb4 = (const float4*)hbuf[wv];
    for (int v = wave; v < N; v += nw) {
        int i0 = rowptr[v], i1 = rowptr[v + 1];
        float acc = 0.f;
        for (int base = i0; base < i1; base += 64) {
            int n = min(64, i1 - base);
            int el = (lane < n) ? esrc[base + lane] : 0;
            int j = 0;
            for (; j + 4 <= n; j += 4) {
                int s0 = __shfl(el, j), s1 = __shfl(el, j + 1);
                int s2 = __shfl(el, j + 2), s3 = __shfl(el, j + 3);
                float f0 = bf2f(Apb[(size_t)s0 * 64 + lane]);
                float f1 = bf2f(Apb[(size_t)s1 * 64 + lane]);
                float f2 = bf2f(Apb[(size_t)s2 * 64 + lane]);
                float f3 = bf2f(Apb[(size_t)s3 * 64 + lane]);
                acc += f0; acc += f1; acc += f2; acc += f3;
            }
            for (; j < n; ++j) {
                int s0 = __shfl(el, j);
                acc += bf2f(Apb[(size_t)s0 * 64 + lane]);
            }
        }
        float dv = dinv[v];
        float h = dv * (acc + bf2f(Apb[(size_t)v * 64 + lane]) * dv) + bias;
        h = h > 0.f ? h : 0.f;
        hbuf[wv][lane] = h;
        asm volatile("s_waitcnt lgkmcnt(0)" ::: "memory");
        float a2 = 0.f;
#pragma unroll
        for (int k4 = 0; k4 < 16; ++k4) {
            float4 hv = hb4[k4];
            a2 += hv.x * w2[4 * k4 + 0] + hv.y * w2[4 * k4 + 1]
                + hv.z * w2[4 * k4 + 2] + hv.w * w2[4 * k4 + 3];
        }
        if (lane < 40) A2pb[(size_t)v * 40 + lane] = f2bf(a2 * dv);
        asm volatile("s_waitcnt lgkmcnt(0)" ::: "memory");
    }
}

// Wave per node: gather bf16 A2p rows, z = dinv*(sum + A2p[v]*dinv) + b2,
// out = log_softmax(softmax(z)) over 40 cols (fp32).
__global__ void layer_out_kernel(const unsigned short* __restrict__ A2pb,
                                 const int* __restrict__ esrc,
                                 const int* __restrict__ rowptr, const float* __restrict__ dinv,
                                 const float* __restrict__ b2, float* __restrict__ out, int N) {
    int gtid = blockIdx.x * blockDim.x + threadIdx.x;
    int wave = gtid >> 6, lane = threadIdx.x & 63;
    int nw = (gridDim.x * blockDim.x) >> 6;
    for (int v = wave; v < N; v += nw) {
        int i0 = rowptr[v], i1 = rowptr[v + 1];
        bool act = lane < 40;
        float acc = 0.f;
        for (int base = i0; base < i1; base += 64) {
            int n = min(64, i1 - base);
            int el = (lane < n) ? esrc[base + lane] : 0;
            int j = 0;
            for (; j + 4 <= n; j += 4) {
                int s0 = __shfl(el, j), s1 = __shfl(el, j + 1);
                int s2 = __shfl(el, j + 2), s3 = __shfl(el, j + 3);
                if (act) {
                    float f0 = bf2f(A2pb[(size_t)s0 * 40 + lane]);
                    float f1 = bf2f(A2pb[(size_t)s1 * 40 + lane]);
                    float f2 = bf2f(A2pb[(size_t)s2 * 40 + lane]);
                    float f3 = bf2f(A2pb[(size_t)s3 * 40 + lane]);
                    acc += f0; acc += f1; acc += f2; acc += f3;
                }
            }
            for (; j < n; ++j) {
                int s0 = __shfl(el, j);
                if (act) acc += bf2f(A2pb[(size_t)s0 * 40 + lane]);
            }
        }
        float dv = dinv[v];
        float z = act ? dv * (acc + bf2f(A2pb[(size_t)v * 40 + lane]) * dv) + b2[lane]
                      : -INFINITY;
        float m = z;
        for (int off = 32; off; off >>= 1) m = fmaxf(m, __shfl_xor(m, off));
        float e = act ? expf(z - m) : 0.f;
        float s = e;
        for (int off = 32; off; off >>= 1) s += __shfl_xor(s, off);
        float p = e / s;
        float m2 = act ? p : -INFINITY;
        for (int off = 32; off; off >>= 1) m2 = fmaxf(m2, __shfl_xor(m2, off));
        float e2 = act ? expf(p - m2) : 0.f;
        float s2 = e2;
        for (int off = 32; off; off >>= 1) s2 += __shfl_xor(s2, off);
        if (act) out[(size_t)v * 40 + lane] = (p - m2) - logf(s2);
    }
}

// ---------------- launch ----------------

extern "C" void kernel_launch(void* const* d_in, const int* in_sizes, int n_in,
                              void* d_out, int out_size, void* d_ws, size_t ws_size,
                              hipStream_t stream) {
    const float* x_in  = (const float*)d_in[0];
    const int*   ei    = (const int*)d_in[1];
    const float* W1_in = (const float*)d_in[2];
    const float* b1_in = (const float*)d_in[3];
    const float* W2_in = (const float*)d_in[4];
    const float* b2_in = (const float*)d_in[5];
    float* out = (float*)d_out;

    int N = in_sizes[0] / 128;
    int E = in_sizes[1] / 2;
    const int* src = ei;
    const int* dst = ei + E;
    int NB = (N + 255) >> 8;            // 256-node bins

    char* ws = (char*)d_ws;
    size_t o = 0;
    auto alloc = [&](size_t bytes) { void* p = ws + o; o += (bytes + 255) & ~(size_t)255; return p; };
    int*   binCnt    = (int*)alloc((size_t)MAXNB * 4);
    int*   binBase   = (int*)alloc(((size_t)MAXNB + 1) * 4);
    int*   binCursor = (int*)alloc((size_t)MAXNB * 4);
    float* dinv      = (float*)alloc((size_t)N * 4);
    int*   rowptr    = (int*)alloc(((size_t)N + 1) * 4);
    int2*  etmp      = (int2*)alloc((size_t)E * 8);
    int*   esrc      = (int*)alloc((size_t)E * 4);
    unsigned short* Apb  = (unsigned short*)alloc((size_t)N * 64 * 2);
    unsigned short* A2pb = (unsigned short*)alloc((size_t)N * 40 * 2);
    float* W1c = (float*)alloc(128 * 64 * 4);
    float* W2c = (float*)alloc(64 * 40 * 4);
    float* b1c = (float*)alloc(64 * 4);
    float* b2c = (float*)alloc(40 * 4);

    // stage small fp32 params
    copy_kernel<<<8, 256, 0, stream>>>((const float4*)W1_in, (float4*)W1c, 128 * 64 / 4);
    copy_kernel<<<4, 256, 0, stream>>>((const float4*)W2_in, (float4*)W2c, 64 * 40 / 4);
    copy_kernel<<<1, 64, 0, stream>>>((const float4*)b1_in, (float4*)b1c, 16);
    copy_kernel<<<1, 64, 0, stream>>>((const float4*)b2_in, (float4*)b2c, 10);

    // binned CSR build
    hipMemsetAsync(binCnt, 0, (size_t)MAXNB * 4, stream);
    binhist_kernel<<<512, 256, 0, stream>>>(dst, binCnt, E, NB);
    binscan_kernel<<<1, 64, 0, stream>>>(binCnt, binBase, binCursor, rowptr, NB, N, E);
    phaseB_kernel<<<(E + CHUNK - 1) / CHUNK, 256, 0, stream>>>(src, dst, binCursor, etmp, E, NB);
    bin2csr_kernel<<<NB, 256, 0, stream>>>(etmp, binBase, rowptr, dinv, esrc, N);

    // layers
    rowgemm_kernel<<<4096, 256, 0, stream>>>(x_in, W1c, dinv, Apb, N);
    layer_mid_kernel<<<2048, 256, 0, stream>>>(Apb, esrc, rowptr, dinv, W2c, b1c, A2pb, N);
    layer_out_kernel<<<2048, 256, 0, stream>>>(A2pb, esrc, rowptr, dinv, b2c, out, N);
}